// Round 11
// baseline (200.915 us; speedup 1.0000x reference)
//
#include <hip/hip_runtime.h>
#include <math.h>
#include <float.h>

#define SNT 512
#define TNT 256
#define N_ROW 65536
#define B_ 32
#define L_ 4
#define T_ 8
#define H_ 8
#define OUT_ 4096
#define CAPW 2560   // per-window candidate cap
#define CAPB 512    // per-sub-bin gather cap

// value-space windows around theoretical N(0,1) quantiles (+-0.035 ~ +-7 sigma)
#define LO0 -0.7095f
#define HI0 -0.6395f
#define LO1 -0.0350f
#define HI1  0.0350f
#define LO2  0.6395f
#define HI2  0.7095f
#define SBS (128.0f / 0.07f)   // sub-bin scale within a window

// ws layout (float offsets)
#define XWS_OFF  0                          // 32*224 = 7168
#define FEAT_OFF 7168                       // 32*32
#define UV_OFF   8192                       // 4*L*B*4096 = 2097152
#define UV_MSTRIDE ((size_t)L_ * B_ * OUT_) // 524288

__device__ __forceinline__ unsigned f2k(float f) {
    unsigned u = __float_as_uint(f);
    return (u & 0x80000000u) ? ~u : (u | 0x80000000u);
}
__device__ __forceinline__ float k2f(unsigned k) {
    unsigned u = (k & 0x80000000u) ? (k ^ 0x80000000u) : ~k;
    return __uint_as_float(u);
}

// ---------------- stats kernel: one block per row, histogram-free, SW-pipelined ----------------
__global__ __launch_bounds__(SNT, 8) void stats_kernel(const float* __restrict__ in,
                                                       float* __restrict__ x_ws) {
    const int row = blockIdx.x;                 // row = (l*T + t)*B + b
    const int tid = threadIdx.x;
    const int wid = tid >> 6;
    const int lane = tid & 63;
    const float4* __restrict__ p4 = (const float4*)(in + (size_t)row * N_ROW);

    __shared__ float cand[3][CAPW];             // 30 KB
    __shared__ float bbuf[CAPB];                // 2 KB
    __shared__ unsigned shist[128];
    __shared__ unsigned warpsum[8];
    __shared__ float4 redw[8];
    __shared__ int s_wcnt[3];
    __shared__ int s_cb[3];
    __shared__ int s_flag[6];
    __shared__ float s_qv[6];
    __shared__ int s_bc;
    __shared__ unsigned s_bidx, s_brem, s_bcnt;
    __shared__ unsigned s_dig, s_rdig;

    const unsigned ranks[6] = {16383u, 16384u, 32767u, 32768u, 49151u, 49152u};

    if (tid < 3) { s_wcnt[tid] = 0; s_cb[tid] = 0; }
    __syncthreads();

    // ---- pass A: stats + 3 below-counts + window compaction, double-buffered loads ----
    float s = 0.f, s2 = 0.f, mn = FLT_MAX, mx = -FLT_MAX;
    int cb0 = 0, cb1 = 0, cb2 = 0;

    auto proc = [&](float x) {
        s += x; s2 = fmaf(x, x, s2);
        mn = fminf(mn, x); mx = fmaxf(mx, x);
        bool b0 = x < LO0, b1 = x < LO1, b2 = x < LO2;
        bool h0 = x < HI0, h1 = x < HI1, h2 = x < HI2;
        cb0 += b0; cb1 += b1; cb2 += b2;
        bool w0 = h0 && !b0, w1 = h1 && !b1, w2 = h2 && !b2;
        if (w0 || w1 || w2) {
            int w = w1 ? 1 : (w2 ? 2 : 0);
            int t = atomicAdd(&s_wcnt[w], 1);
            if (t < CAPW) cand[w][t] = x;
        }
    };

    // software pipeline: prefetch next iteration's 4 float4 before processing current
    {
        float4 n0 = p4[tid];
        float4 n1 = p4[tid + SNT];
        float4 n2 = p4[tid + 2 * SNT];
        float4 n3 = p4[tid + 3 * SNT];
#pragma unroll
        for (int it = 0; it < N_ROW / 4 / SNT / 4; it++) {   // 8 iterations
            float4 v0 = n0, v1 = n1, v2 = n2, v3 = n3;
            if (it < N_ROW / 4 / SNT / 4 - 1) {
                int nb = (it + 1) * 4 * SNT + tid;
                n0 = p4[nb];
                n1 = p4[nb + SNT];
                n2 = p4[nb + 2 * SNT];
                n3 = p4[nb + 3 * SNT];
            }
            proc(v0.x); proc(v0.y); proc(v0.z); proc(v0.w);
            proc(v1.x); proc(v1.y); proc(v1.z); proc(v1.w);
            proc(v2.x); proc(v2.y); proc(v2.z); proc(v2.w);
            proc(v3.x); proc(v3.y); proc(v3.z); proc(v3.w);
        }
    }

    // wave reductions
#pragma unroll
    for (int off = 32; off > 0; off >>= 1) {
        s += __shfl_xor(s, off);
        s2 += __shfl_xor(s2, off);
        mn = fminf(mn, __shfl_xor(mn, off));
        mx = fmaxf(mx, __shfl_xor(mx, off));
        cb0 += __shfl_xor(cb0, off);
        cb1 += __shfl_xor(cb1, off);
        cb2 += __shfl_xor(cb2, off);
    }
    if (lane == 0) {
        redw[wid] = make_float4(s, s2, mn, mx);
        atomicAdd(&s_cb[0], cb0);
        atomicAdd(&s_cb[1], cb1);
        atomicAdd(&s_cb[2], cb2);
    }
    __syncthreads();
    if (tid == 0) {
        float4 a = redw[0];
#pragma unroll
        for (int w = 1; w < 8; w++) {
            float4 b = redw[w];
            a.x += b.x; a.y += b.y;
            a.z = fminf(a.z, b.z); a.w = fmaxf(a.w, b.w);
        }
        redw[0] = a;
        for (int i = 0; i < 6; i++) {
            int w = i >> 1;
            long rl = (long)ranks[i] - (long)s_cb[w];
            int ok = (rl >= 0) && (rl < (long)s_wcnt[w]) && (s_wcnt[w] <= CAPW);
            s_flag[i] = !ok;
        }
    }
    __syncthreads();

    // ---- fast select: per window, 128-sub-bin narrow then exact count-select ----
    const float wlo[3] = {LO0, LO1, LO2};
    for (int w = 0; w < 3; w++) {
        if (s_flag[2 * w] && s_flag[2 * w + 1]) continue;
        int c = s_wcnt[w];
        float lo = wlo[w];
        if (tid < 128) shist[tid] = 0u;
        __syncthreads();
        for (int j = tid; j < c; j += SNT) {
            int sb = (int)((cand[w][j] - lo) * SBS);
            sb = sb < 0 ? 0 : (sb > 127 ? 127 : sb);
            atomicAdd(&shist[sb], 1u);
        }
        __syncthreads();
        if (wid == 0) {
            unsigned a0 = shist[2 * lane], a1 = shist[2 * lane + 1];
            unsigned t = a0 + a1, sc = t;
#pragma unroll
            for (int d = 1; d < 64; d <<= 1) {
                unsigned n = __shfl_up(sc, d);
                if (lane >= d) sc += n;
            }
            unsigned ex = sc - t;
            shist[2 * lane] = ex + a0;
            shist[2 * lane + 1] = ex + a0 + a1;
        }
        __syncthreads();
        for (int ii = 0; ii < 2; ii++) {
            int i = 2 * w + ii;
            if (s_flag[i]) continue;
            unsigned rl = ranks[i] - (unsigned)s_cb[w];
            if (tid < 128) {
                unsigned cc = shist[tid];
                unsigned cbp = tid ? shist[tid - 1] : 0u;
                if (rl < cc && rl >= cbp) {
                    s_bidx = (unsigned)tid; s_brem = rl - cbp; s_bcnt = cc - cbp;
                }
            }
            if (tid == 0) s_bc = 0;
            __syncthreads();
            if (s_bcnt > CAPB) {            // pathological tie cluster -> exact fallback
                if (tid == 0) s_flag[i] = 1;
                __syncthreads();
                continue;
            }
            unsigned bidx = s_bidx;
            for (int j = tid; j < c; j += SNT) {
                float x = cand[w][j];
                int sb = (int)((x - lo) * SBS);
                sb = sb < 0 ? 0 : (sb > 127 ? 127 : sb);
                if ((unsigned)sb == bidx) { int q = atomicAdd(&s_bc, 1); bbuf[q] = x; }
            }
            __syncthreads();
            int bc = s_bc;
            unsigned rem = s_brem;
            for (int j = tid; j < bc; j += SNT) {
                float x = bbuf[j];
                int less = 0, eq = 0;
                for (int k = 0; k < bc; k++) {
                    float y = bbuf[k];
                    less += (y < x); eq += (y == x);
                }
                if ((unsigned)less <= rem && rem < (unsigned)(less + eq)) s_qv[i] = x;
            }
            __syncthreads();
        }
    }

    // ---- exact fallback: 3-level radix select on float keys (row from L2) ----
    {
        unsigned* h2 = (unsigned*)&cand[0][0];   // reuse 8 KB
        for (int i = 0; i < 6; i++) {
            if (!s_flag[i]) continue;
            unsigned rank = ranks[i];
            unsigned prefix = 0;
            for (int level = 0; level < 3; level++) {
                int nb = (level == 2) ? 1024 : 2048;
                for (int j = tid; j < nb; j += SNT) h2[j] = 0u;
                __syncthreads();
                for (int j = tid; j < N_ROW / 4; j += SNT) {
                    float4 v = p4[j];
                    float xs[4] = {v.x, v.y, v.z, v.w};
#pragma unroll
                    for (int k = 0; k < 4; k++) {
                        unsigned key = f2k(xs[k]);
                        if (level == 0) atomicAdd(&h2[key >> 21], 1u);
                        else if (level == 1) { if ((key >> 21) == prefix) atomicAdd(&h2[(key >> 10) & 2047u], 1u); }
                        else { if ((key >> 10) == prefix) atomicAdd(&h2[key & 1023u], 1u); }
                    }
                }
                __syncthreads();
                int per = nb / SNT;              // 4 or 2
                unsigned ls[4]; unsigned acc = 0;
                int base = tid * per;
                for (int k = 0; k < per; k++) { acc += h2[base + k]; ls[k] = acc; }
                unsigned sc = acc;
#pragma unroll
                for (int d = 1; d < 64; d <<= 1) {
                    unsigned n = __shfl_up(sc, d);
                    if (lane >= d) sc += n;
                }
                if (lane == 63) warpsum[wid] = sc;
                __syncthreads();
                unsigned woff = 0;
                for (int ww = 0; ww < wid; ww++) woff += warpsum[ww];
                unsigned ex = woff + sc - acc;
                for (int k = 0; k < per; k++) h2[base + k] = ls[k] + ex;
                __syncthreads();
                for (int k = 0; k < per; k++) {
                    int j = base + k;
                    unsigned cc = h2[j];
                    unsigned cbp = j ? h2[j - 1] : 0u;
                    if (rank < cc && rank >= cbp) { s_dig = (unsigned)j; s_rdig = rank - cbp; }
                }
                __syncthreads();
                unsigned dig = s_dig;
                rank = s_rdig;
                prefix = (level == 0) ? dig : ((prefix << 11) | dig);
                __syncthreads();
            }
            if (tid == 0) s_qv[i] = k2f(prefix);  // prefix = full key
            __syncthreads();
        }
    }

    if (tid == 0) {
        double ssum = (double)redw[0].x;
        double ssq = (double)redw[0].y;
        float mean = (float)(ssum / 65536.0);
        float var = (float)((ssq - ssum * ssum / 65536.0) / 65535.0);
        float q25 = s_qv[0] + 0.75f * (s_qv[1] - s_qv[0]);
        float q50 = s_qv[2] + 0.5f * (s_qv[3] - s_qv[2]);
        float q75 = s_qv[4] + 0.25f * (s_qv[5] - s_qv[4]);
        int lt = row / B_;
        int b = row % B_;
        float* o = x_ws + XWS_OFF + b * 224 + lt * 7;
        o[0] = mean; o[1] = var; o[2] = redw[0].z;
        o[3] = q25;  o[4] = q50; o[5] = q75; o[6] = redw[0].w;
    }
}

// ---------------- feature net: one wave per batch row ----------------
__global__ __launch_bounds__(64) void featnet_kernel(
    const float* __restrict__ ws_in,
    const float* __restrict__ W1, const float* __restrict__ b1,
    const float* __restrict__ lng, const float* __restrict__ lnb,
    const float* __restrict__ W2, const float* __restrict__ b2,
    float* __restrict__ feat_ws) {
    int b = blockIdx.x;
    int j = threadIdx.x;   // 0..63
    __shared__ float xs[224];
    __shared__ float h1s[64];
    const float* x = ws_in + XWS_OFF + b * 224;
    for (int k = j; k < 224; k += 64) xs[k] = x[k];
    __syncthreads();
    float acc = b1[j];
    for (int k = 0; k < 224; k++) acc += xs[k] * W1[k * 64 + j];
    float s = acc, s2 = acc * acc;
    for (int off = 32; off > 0; off >>= 1) {
        s += __shfl_xor(s, off);
        s2 += __shfl_xor(s2, off);
    }
    float mu = s * (1.f / 64.f);
    float var = s2 * (1.f / 64.f) - mu * mu;       // biased
    float hn = (acc - mu) * rsqrtf(var + 1e-5f) * lng[j] + lnb[j];
    float ge = 0.5f * hn * (1.f + erff(hn * 0.70710678118654752f));  // exact GELU
    h1s[j] = ge;
    __syncthreads();
    if (j < 32) {
        float a2 = b2[j];
        for (int k = 0; k < 64; k++) a2 += h1s[k] * W2[k * 32 + j];
        feat_ws[b * 32 + j] = a2;
    }
}

// ---------------- uv kernel: weights read exactly once; one m per block ----------------
__global__ __launch_bounds__(TNT) void uv_kernel(
    const float* __restrict__ feat,
    const float* __restrict__ MU_W, const float* __restrict__ MU_b,
    const float* __restrict__ MV_W, const float* __restrict__ MV_b,
    const float* __restrict__ NU_W, const float* __restrict__ NU_b,
    const float* __restrict__ NV_W, const float* __restrict__ NV_b,
    float* __restrict__ uv) {
    const int bid = blockIdx.x;           // m*128 + l*32 + chunk
    const int m = bid >> 7;
    const int l = (bid >> 5) & 3;
    const int c0 = (bid & 31) * 128;
    const int tid = threadIdx.x;

    __shared__ float fs[32][32];
    __shared__ float Wt[32][128];

    const float* W; const float* Bv;
    if (m == 0)      { W = MU_W; Bv = MU_b; }
    else if (m == 1) { W = MV_W; Bv = MV_b; }
    else if (m == 2) { W = NU_W; Bv = NU_b; }
    else             { W = NV_W; Bv = NV_b; }
    W += (size_t)l * 32 * OUT_ + c0;

    for (int i = tid; i < 1024; i += TNT) fs[i >> 5][i & 31] = feat[i];
    for (int i = tid; i < 32 * 128; i += TNT) {
        int f = i >> 7, c = i & 127;
        Wt[f][c] = W[(size_t)f * OUT_ + c];
    }
    __syncthreads();

    const int col = tid & 127;
    const int bh = tid >> 7;
    float bias = Bv[(size_t)l * OUT_ + c0 + col];
    float* dst = uv + (size_t)m * UV_MSTRIDE + (size_t)l * B_ * OUT_ + c0 + col;
    for (int k = 0; k < 16; k++) {
        int b = bh * 16 + k;
        float acc = bias;
#pragma unroll
        for (int f = 0; f < 32; f++) acc += fs[b][f] * Wt[f][col];
        dst[(size_t)b * OUT_] = acc;
    }
}

// ---------------- expand kernel: U@V + 0.1*I, float4 stores ----------------
__global__ __launch_bounds__(TNT) void expand_kernel(const float* __restrict__ uv,
                                                     float* __restrict__ out) {
    const int id = blockIdx.x;            // l*256 + b*8 + h
    const int l = id >> 8;
    const int b = (id >> 3) & 31;
    const int h = id & 7;
    const int tid = threadIdx.x;

    __shared__ float UM[512], VM[512], UN[512], VN[512];
    size_t base_lb = (size_t)l * B_ * OUT_ + (size_t)b * OUT_ + (size_t)h * 512;
    for (int i = tid; i < 512; i += TNT) {
        UM[i] = uv[0 * UV_MSTRIDE + base_lb + i];
        VM[i] = uv[1 * UV_MSTRIDE + base_lb + i];
        UN[i] = uv[2 * UV_MSTRIDE + base_lb + i];
        VN[i] = uv[3 * UV_MSTRIDE + base_lb + i];
    }
    __syncthreads();

    int d = tid >> 2;
    int eb = (tid & 3) * 16;
    size_t obase = (size_t)id * 4096 + (size_t)d * 64 + eb;
    float* outN = out + (size_t)L_ * B_ * H_ * 4096;

    float um[8], un[8];
#pragma unroll
    for (int r = 0; r < 8; r++) { um[r] = UM[d * 8 + r]; un[r] = UN[d * 8 + r]; }

    float rm[16], rn[16];
#pragma unroll
    for (int e = 0; e < 16; e++) {
        float am = 0.f, an = 0.f;
#pragma unroll
        for (int r = 0; r < 8; r++) {
            am += um[r] * VM[r * 64 + eb + e];
            an += un[r] * VN[r * 64 + eb + e];
        }
        if (d == eb + e) { am += 0.1f; an += 0.1f; }
        rm[e] = am; rn[e] = an;
    }
    float4* om4 = (float4*)(out + obase);
    float4* on4 = (float4*)(outN + obase);
#pragma unroll
    for (int q = 0; q < 4; q++) {
        om4[q] = make_float4(rm[4 * q], rm[4 * q + 1], rm[4 * q + 2], rm[4 * q + 3]);
        on4[q] = make_float4(rn[4 * q], rn[4 * q + 1], rn[4 * q + 2], rn[4 * q + 3]);
    }
}

extern "C" void kernel_launch(void* const* d_in, const int* in_sizes, int n_in,
                              void* d_out, int out_size, void* d_ws, size_t ws_size,
                              hipStream_t stream) {
    const float* wsfeat = (const float*)d_in[0];
    const float* fn_W1 = (const float*)d_in[1];
    const float* fn_b1 = (const float*)d_in[2];
    const float* ln_g = (const float*)d_in[3];
    const float* ln_b = (const float*)d_in[4];
    const float* fn_W2 = (const float*)d_in[5];
    const float* fn_b2 = (const float*)d_in[6];
    const float* MU_W = (const float*)d_in[7];
    const float* MU_b = (const float*)d_in[8];
    const float* MV_W = (const float*)d_in[9];
    const float* MV_b = (const float*)d_in[10];
    const float* NU_W = (const float*)d_in[11];
    const float* NU_b = (const float*)d_in[12];
    const float* NV_W = (const float*)d_in[13];
    const float* NV_b = (const float*)d_in[14];

    float* ws = (float*)d_ws;
    float* feat_ws = ws + FEAT_OFF;
    float* uv = ws + UV_OFF;

    stats_kernel<<<L_ * T_ * B_, SNT, 0, stream>>>(wsfeat, ws);
    featnet_kernel<<<B_, 64, 0, stream>>>(ws, fn_W1, fn_b1, ln_g, ln_b, fn_W2, fn_b2, feat_ws);
    uv_kernel<<<4 * L_ * 32, TNT, 0, stream>>>(feat_ws, MU_W, MU_b, MV_W, MV_b,
                                               NU_W, NU_b, NV_W, NV_b, uv);
    expand_kernel<<<L_ * B_ * H_, TNT, 0, stream>>>(uv, (float*)d_out);
}

// Round 12
// 107.348 us; speedup vs baseline: 1.8716x; 1.8716x over previous
//
#include <hip/hip_runtime.h>
#include <math.h>
#include <float.h>

#define SNT 512
#define TNT 256
#define N_ROW 65536
#define B_ 32
#define L_ 4
#define T_ 8
#define H_ 8
#define OUT_ 4096
#define CAPW 2560   // per-window candidate cap
#define CAPB 512    // per-sub-bin gather cap

// value-space windows around theoretical N(0,1) quantiles (+-0.035 ~ +-7 sigma)
#define LO0 -0.7095f
#define HI0 -0.6395f
#define LO1 -0.0350f
#define HI1  0.0350f
#define LO2  0.6395f
#define HI2  0.7095f
#define SBS (128.0f / 0.07f)   // sub-bin scale within a window

// ws layout (float offsets)
#define XWS_OFF  0                          // 32*224 = 7168
#define FEAT_OFF 7168                       // 32*32
#define UV_OFF   8192                       // 4*L*B*4096 = 2097152
#define UV_MSTRIDE ((size_t)L_ * B_ * OUT_) // 524288

__device__ __forceinline__ unsigned f2k(float f) {
    unsigned u = __float_as_uint(f);
    return (u & 0x80000000u) ? ~u : (u | 0x80000000u);
}
__device__ __forceinline__ float k2f(unsigned k) {
    unsigned u = (k & 0x80000000u) ? (k ^ 0x80000000u) : ~k;
    return __uint_as_float(u);
}

// ---------------- stats kernel: one block per row, histogram-free (R10 proven) ----------------
// NOTE: no manual prefetch/unroll here — under the (512,8) 64-VGPR budget a SW pipeline
// spills to scratch (R11: WRITE_SIZE 30KB -> 194MB, 85 -> 195us). Compiler schedule wins.
__global__ __launch_bounds__(SNT, 8) void stats_kernel(const float* __restrict__ in,
                                                       float* __restrict__ x_ws) {
    const int row = blockIdx.x;                 // row = (l*T + t)*B + b
    const int tid = threadIdx.x;
    const int wid = tid >> 6;
    const int lane = tid & 63;
    const float4* __restrict__ p4 = (const float4*)(in + (size_t)row * N_ROW);

    __shared__ float cand[3][CAPW];             // 30 KB
    __shared__ float bbuf[CAPB];                // 2 KB
    __shared__ unsigned shist[128];
    __shared__ unsigned warpsum[8];
    __shared__ float4 redw[8];
    __shared__ int s_wcnt[3];
    __shared__ int s_cb[3];
    __shared__ int s_flag[6];
    __shared__ float s_qv[6];
    __shared__ int s_bc;
    __shared__ unsigned s_bidx, s_brem, s_bcnt;
    __shared__ unsigned s_dig, s_rdig;

    const unsigned ranks[6] = {16383u, 16384u, 32767u, 32768u, 49151u, 49152u};

    if (tid < 3) { s_wcnt[tid] = 0; s_cb[tid] = 0; }
    __syncthreads();

    // ---- pass A: stats + 3 below-counts + window compaction (no per-element LDS) ----
    float s = 0.f, s2 = 0.f, mn = FLT_MAX, mx = -FLT_MAX;
    int cb0 = 0, cb1 = 0, cb2 = 0;

    auto proc = [&](float x) {
        s += x; s2 = fmaf(x, x, s2);
        mn = fminf(mn, x); mx = fmaxf(mx, x);
        bool b0 = x < LO0, b1 = x < LO1, b2 = x < LO2;
        bool h0 = x < HI0, h1 = x < HI1, h2 = x < HI2;
        cb0 += b0; cb1 += b1; cb2 += b2;
        bool w0 = h0 && !b0, w1 = h1 && !b1, w2 = h2 && !b2;
        if (w0 || w1 || w2) {
            int w = w1 ? 1 : (w2 ? 2 : 0);
            int t = atomicAdd(&s_wcnt[w], 1);
            if (t < CAPW) cand[w][t] = x;
        }
    };

    for (int it = 0; it < N_ROW / 4 / SNT / 4; it++) {
        int base = it * 4 * SNT + tid;
        float4 v0 = p4[base];
        float4 v1 = p4[base + SNT];
        float4 v2 = p4[base + 2 * SNT];
        float4 v3 = p4[base + 3 * SNT];
        proc(v0.x); proc(v0.y); proc(v0.z); proc(v0.w);
        proc(v1.x); proc(v1.y); proc(v1.z); proc(v1.w);
        proc(v2.x); proc(v2.y); proc(v2.z); proc(v2.w);
        proc(v3.x); proc(v3.y); proc(v3.z); proc(v3.w);
    }

    // wave reductions
#pragma unroll
    for (int off = 32; off > 0; off >>= 1) {
        s += __shfl_xor(s, off);
        s2 += __shfl_xor(s2, off);
        mn = fminf(mn, __shfl_xor(mn, off));
        mx = fmaxf(mx, __shfl_xor(mx, off));
        cb0 += __shfl_xor(cb0, off);
        cb1 += __shfl_xor(cb1, off);
        cb2 += __shfl_xor(cb2, off);
    }
    if (lane == 0) {
        redw[wid] = make_float4(s, s2, mn, mx);
        atomicAdd(&s_cb[0], cb0);
        atomicAdd(&s_cb[1], cb1);
        atomicAdd(&s_cb[2], cb2);
    }
    __syncthreads();
    if (tid == 0) {
        float4 a = redw[0];
#pragma unroll
        for (int w = 1; w < 8; w++) {
            float4 b = redw[w];
            a.x += b.x; a.y += b.y;
            a.z = fminf(a.z, b.z); a.w = fmaxf(a.w, b.w);
        }
        redw[0] = a;
        for (int i = 0; i < 6; i++) {
            int w = i >> 1;
            long rl = (long)ranks[i] - (long)s_cb[w];
            int ok = (rl >= 0) && (rl < (long)s_wcnt[w]) && (s_wcnt[w] <= CAPW);
            s_flag[i] = !ok;
        }
    }
    __syncthreads();

    // ---- fast select: per window, 128-sub-bin narrow then exact count-select ----
    const float wlo[3] = {LO0, LO1, LO2};
    for (int w = 0; w < 3; w++) {
        if (s_flag[2 * w] && s_flag[2 * w + 1]) continue;
        int c = s_wcnt[w];
        float lo = wlo[w];
        if (tid < 128) shist[tid] = 0u;
        __syncthreads();
        for (int j = tid; j < c; j += SNT) {
            int sb = (int)((cand[w][j] - lo) * SBS);
            sb = sb < 0 ? 0 : (sb > 127 ? 127 : sb);
            atomicAdd(&shist[sb], 1u);
        }
        __syncthreads();
        if (wid == 0) {
            unsigned a0 = shist[2 * lane], a1 = shist[2 * lane + 1];
            unsigned t = a0 + a1, sc = t;
#pragma unroll
            for (int d = 1; d < 64; d <<= 1) {
                unsigned n = __shfl_up(sc, d);
                if (lane >= d) sc += n;
            }
            unsigned ex = sc - t;
            shist[2 * lane] = ex + a0;
            shist[2 * lane + 1] = ex + a0 + a1;
        }
        __syncthreads();
        for (int ii = 0; ii < 2; ii++) {
            int i = 2 * w + ii;
            if (s_flag[i]) continue;
            unsigned rl = ranks[i] - (unsigned)s_cb[w];
            if (tid < 128) {
                unsigned cc = shist[tid];
                unsigned cbp = tid ? shist[tid - 1] : 0u;
                if (rl < cc && rl >= cbp) {
                    s_bidx = (unsigned)tid; s_brem = rl - cbp; s_bcnt = cc - cbp;
                }
            }
            if (tid == 0) s_bc = 0;
            __syncthreads();
            if (s_bcnt > CAPB) {            // pathological tie cluster -> exact fallback
                if (tid == 0) s_flag[i] = 1;
                __syncthreads();
                continue;
            }
            unsigned bidx = s_bidx;
            for (int j = tid; j < c; j += SNT) {
                float x = cand[w][j];
                int sb = (int)((x - lo) * SBS);
                sb = sb < 0 ? 0 : (sb > 127 ? 127 : sb);
                if ((unsigned)sb == bidx) { int q = atomicAdd(&s_bc, 1); bbuf[q] = x; }
            }
            __syncthreads();
            int bc = s_bc;
            unsigned rem = s_brem;
            for (int j = tid; j < bc; j += SNT) {
                float x = bbuf[j];
                int less = 0, eq = 0;
                for (int k = 0; k < bc; k++) {
                    float y = bbuf[k];
                    less += (y < x); eq += (y == x);
                }
                if ((unsigned)less <= rem && rem < (unsigned)(less + eq)) s_qv[i] = x;
            }
            __syncthreads();
        }
    }

    // ---- exact fallback: 3-level radix select on float keys (row from L2) ----
    {
        unsigned* h2 = (unsigned*)&cand[0][0];   // reuse 8 KB
        for (int i = 0; i < 6; i++) {
            if (!s_flag[i]) continue;
            unsigned rank = ranks[i];
            unsigned prefix = 0;
            for (int level = 0; level < 3; level++) {
                int nb = (level == 2) ? 1024 : 2048;
                for (int j = tid; j < nb; j += SNT) h2[j] = 0u;
                __syncthreads();
                for (int j = tid; j < N_ROW / 4; j += SNT) {
                    float4 v = p4[j];
                    float xs[4] = {v.x, v.y, v.z, v.w};
#pragma unroll
                    for (int k = 0; k < 4; k++) {
                        unsigned key = f2k(xs[k]);
                        if (level == 0) atomicAdd(&h2[key >> 21], 1u);
                        else if (level == 1) { if ((key >> 21) == prefix) atomicAdd(&h2[(key >> 10) & 2047u], 1u); }
                        else { if ((key >> 10) == prefix) atomicAdd(&h2[key & 1023u], 1u); }
                    }
                }
                __syncthreads();
                int per = nb / SNT;              // 4 or 2
                unsigned ls[4]; unsigned acc = 0;
                int base = tid * per;
                for (int k = 0; k < per; k++) { acc += h2[base + k]; ls[k] = acc; }
                unsigned sc = acc;
#pragma unroll
                for (int d = 1; d < 64; d <<= 1) {
                    unsigned n = __shfl_up(sc, d);
                    if (lane >= d) sc += n;
                }
                if (lane == 63) warpsum[wid] = sc;
                __syncthreads();
                unsigned woff = 0;
                for (int ww = 0; ww < wid; ww++) woff += warpsum[ww];
                unsigned ex = woff + sc - acc;
                for (int k = 0; k < per; k++) h2[base + k] = ls[k] + ex;
                __syncthreads();
                for (int k = 0; k < per; k++) {
                    int j = base + k;
                    unsigned cc = h2[j];
                    unsigned cbp = j ? h2[j - 1] : 0u;
                    if (rank < cc && rank >= cbp) { s_dig = (unsigned)j; s_rdig = rank - cbp; }
                }
                __syncthreads();
                unsigned dig = s_dig;
                rank = s_rdig;
                prefix = (level == 0) ? dig : ((prefix << 11) | dig);
                __syncthreads();
            }
            if (tid == 0) s_qv[i] = k2f(prefix);  // prefix = full key
            __syncthreads();
        }
    }

    if (tid == 0) {
        double ssum = (double)redw[0].x;
        double ssq = (double)redw[0].y;
        float mean = (float)(ssum / 65536.0);
        float var = (float)((ssq - ssum * ssum / 65536.0) / 65535.0);
        float q25 = s_qv[0] + 0.75f * (s_qv[1] - s_qv[0]);
        float q50 = s_qv[2] + 0.5f * (s_qv[3] - s_qv[2]);
        float q75 = s_qv[4] + 0.25f * (s_qv[5] - s_qv[4]);
        int lt = row / B_;
        int b = row % B_;
        float* o = x_ws + XWS_OFF + b * 224 + lt * 7;
        o[0] = mean; o[1] = var; o[2] = redw[0].z;
        o[3] = q25;  o[4] = q50; o[5] = q75; o[6] = redw[0].w;
    }
}

// ---------------- feature net: one wave per batch row ----------------
__global__ __launch_bounds__(64) void featnet_kernel(
    const float* __restrict__ ws_in,
    const float* __restrict__ W1, const float* __restrict__ b1,
    const float* __restrict__ lng, const float* __restrict__ lnb,
    const float* __restrict__ W2, const float* __restrict__ b2,
    float* __restrict__ feat_ws) {
    int b = blockIdx.x;
    int j = threadIdx.x;   // 0..63
    __shared__ float xs[224];
    __shared__ float h1s[64];
    const float* x = ws_in + XWS_OFF + b * 224;
    for (int k = j; k < 224; k += 64) xs[k] = x[k];
    __syncthreads();
    float acc = b1[j];
    for (int k = 0; k < 224; k++) acc += xs[k] * W1[k * 64 + j];
    float s = acc, s2 = acc * acc;
    for (int off = 32; off > 0; off >>= 1) {
        s += __shfl_xor(s, off);
        s2 += __shfl_xor(s2, off);
    }
    float mu = s * (1.f / 64.f);
    float var = s2 * (1.f / 64.f) - mu * mu;       // biased
    float hn = (acc - mu) * rsqrtf(var + 1e-5f) * lng[j] + lnb[j];
    float ge = 0.5f * hn * (1.f + erff(hn * 0.70710678118654752f));  // exact GELU
    h1s[j] = ge;
    __syncthreads();
    if (j < 32) {
        float a2 = b2[j];
        for (int k = 0; k < 64; k++) a2 += h1s[k] * W2[k * 32 + j];
        feat_ws[b * 32 + j] = a2;
    }
}

// ---------------- uv kernel: weights read exactly once; one m per block ----------------
__global__ __launch_bounds__(TNT) void uv_kernel(
    const float* __restrict__ feat,
    const float* __restrict__ MU_W, const float* __restrict__ MU_b,
    const float* __restrict__ MV_W, const float* __restrict__ MV_b,
    const float* __restrict__ NU_W, const float* __restrict__ NU_b,
    const float* __restrict__ NV_W, const float* __restrict__ NV_b,
    float* __restrict__ uv) {
    const int bid = blockIdx.x;           // m*128 + l*32 + chunk
    const int m = bid >> 7;
    const int l = (bid >> 5) & 3;
    const int c0 = (bid & 31) * 128;
    const int tid = threadIdx.x;

    __shared__ float fs[32][32];
    __shared__ float Wt[32][128];

    const float* W; const float* Bv;
    if (m == 0)      { W = MU_W; Bv = MU_b; }
    else if (m == 1) { W = MV_W; Bv = MV_b; }
    else if (m == 2) { W = NU_W; Bv = NU_b; }
    else             { W = NV_W; Bv = NV_b; }
    W += (size_t)l * 32 * OUT_ + c0;

    for (int i = tid; i < 1024; i += TNT) fs[i >> 5][i & 31] = feat[i];
    for (int i = tid; i < 32 * 128; i += TNT) {
        int f = i >> 7, c = i & 127;
        Wt[f][c] = W[(size_t)f * OUT_ + c];
    }
    __syncthreads();

    const int col = tid & 127;
    const int bh = tid >> 7;
    float bias = Bv[(size_t)l * OUT_ + c0 + col];
    float* dst = uv + (size_t)m * UV_MSTRIDE + (size_t)l * B_ * OUT_ + c0 + col;
    for (int k = 0; k < 16; k++) {
        int b = bh * 16 + k;
        float acc = bias;
#pragma unroll
        for (int f = 0; f < 32; f++) acc += fs[b][f] * Wt[f][col];
        dst[(size_t)b * OUT_] = acc;
    }
}

// ---------------- expand kernel: U@V + 0.1*I, float4 stores ----------------
__global__ __launch_bounds__(TNT) void expand_kernel(const float* __restrict__ uv,
                                                     float* __restrict__ out) {
    const int id = blockIdx.x;            // l*256 + b*8 + h
    const int l = id >> 8;
    const int b = (id >> 3) & 31;
    const int h = id & 7;
    const int tid = threadIdx.x;

    __shared__ float UM[512], VM[512], UN[512], VN[512];
    size_t base_lb = (size_t)l * B_ * OUT_ + (size_t)b * OUT_ + (size_t)h * 512;
    for (int i = tid; i < 512; i += TNT) {
        UM[i] = uv[0 * UV_MSTRIDE + base_lb + i];
        VM[i] = uv[1 * UV_MSTRIDE + base_lb + i];
        UN[i] = uv[2 * UV_MSTRIDE + base_lb + i];
        VN[i] = uv[3 * UV_MSTRIDE + base_lb + i];
    }
    __syncthreads();

    int d = tid >> 2;
    int eb = (tid & 3) * 16;
    size_t obase = (size_t)id * 4096 + (size_t)d * 64 + eb;
    float* outN = out + (size_t)L_ * B_ * H_ * 4096;

    float um[8], un[8];
#pragma unroll
    for (int r = 0; r < 8; r++) { um[r] = UM[d * 8 + r]; un[r] = UN[d * 8 + r]; }

    float rm[16], rn[16];
#pragma unroll
    for (int e = 0; e < 16; e++) {
        float am = 0.f, an = 0.f;
#pragma unroll
        for (int r = 0; r < 8; r++) {
            am += um[r] * VM[r * 64 + eb + e];
            an += un[r] * VN[r * 64 + eb + e];
        }
        if (d == eb + e) { am += 0.1f; an += 0.1f; }
        rm[e] = am; rn[e] = an;
    }
    float4* om4 = (float4*)(out + obase);
    float4* on4 = (float4*)(outN + obase);
#pragma unroll
    for (int q = 0; q < 4; q++) {
        om4[q] = make_float4(rm[4 * q], rm[4 * q + 1], rm[4 * q + 2], rm[4 * q + 3]);
        on4[q] = make_float4(rn[4 * q], rn[4 * q + 1], rn[4 * q + 2], rn[4 * q + 3]);
    }
}

extern "C" void kernel_launch(void* const* d_in, const int* in_sizes, int n_in,
                              void* d_out, int out_size, void* d_ws, size_t ws_size,
                              hipStream_t stream) {
    const float* wsfeat = (const float*)d_in[0];
    const float* fn_W1 = (const float*)d_in[1];
    const float* fn_b1 = (const float*)d_in[2];
    const float* ln_g = (const float*)d_in[3];
    const float* ln_b = (const float*)d_in[4];
    const float* fn_W2 = (const float*)d_in[5];
    const float* fn_b2 = (const float*)d_in[6];
    const float* MU_W = (const float*)d_in[7];
    const float* MU_b = (const float*)d_in[8];
    const float* MV_W = (const float*)d_in[9];
    const float* MV_b = (const float*)d_in[10];
    const float* NU_W = (const float*)d_in[11];
    const float* NU_b = (const float*)d_in[12];
    const float* NV_W = (const float*)d_in[13];
    const float* NV_b = (const float*)d_in[14];

    float* ws = (float*)d_ws;
    float* feat_ws = ws + FEAT_OFF;
    float* uv = ws + UV_OFF;

    stats_kernel<<<L_ * T_ * B_, SNT, 0, stream>>>(wsfeat, ws);
    featnet_kernel<<<B_, 64, 0, stream>>>(ws, fn_W1, fn_b1, ln_g, ln_b, fn_W2, fn_b2, feat_ws);
    uv_kernel<<<4 * L_ * 32, TNT, 0, stream>>>(feat_ws, MU_W, MU_b, MV_W, MV_b,
                                               NU_W, NU_b, NV_W, NV_b, uv);
    expand_kernel<<<L_ * B_ * H_, TNT, 0, stream>>>(uv, (float*)d_out);
}